// Round 1
// baseline (564.393 us; speedup 1.0000x reference)
//
#include <hip/hip_runtime.h>
#include <stdint.h>

#define H_DIM 2048
#define E_NUM 8
#define D_DIM 2048
#define NTOK 4096
#define BM 128
#define BN 128
#define BK 32

typedef __bf16 bf16x8 __attribute__((ext_vector_type(8)));
typedef float f32x4 __attribute__((ext_vector_type(4)));

__device__ __forceinline__ unsigned short f2bf(float f) {
    union { float f; uint32_t u; } c; c.f = f;
    uint32_t r = (c.u + 0x7FFFu + ((c.u >> 16) & 1u)) >> 16;
    return (unsigned short)r;
}
__device__ __forceinline__ float bf2f(unsigned short h) {
    union { float f; uint32_t u; } c; c.u = ((uint32_t)h) << 16;
    return c.f;
}

// ---------------- K1: router (logits -> top2 -> gates -> scatter lists) ------
__global__ __launch_bounds__(256) void router_kernel(
    const float* __restrict__ x, const float* __restrict__ rw,
    const float* __restrict__ rb, int* __restrict__ counts,
    uint32_t* __restrict__ tok, float* __restrict__ gate) {
    int t = blockIdx.x;
    const float* xr = x + (size_t)t * H_DIM;
    float p[E_NUM];
#pragma unroll
    for (int e = 0; e < E_NUM; e++) p[e] = 0.f;
    for (int h = threadIdx.x; h < H_DIM; h += 256) {
        float xv = xr[h];
        const float* r = rw + (size_t)h * E_NUM;
#pragma unroll
        for (int e = 0; e < E_NUM; e++) p[e] += xv * r[e];
    }
#pragma unroll
    for (int e = 0; e < E_NUM; e++) {
#pragma unroll
        for (int off = 32; off > 0; off >>= 1) p[e] += __shfl_down(p[e], off, 64);
    }
    __shared__ float red[4][E_NUM];
    int lane = threadIdx.x & 63, w = threadIdx.x >> 6;
    if (lane == 0) {
#pragma unroll
        for (int e = 0; e < E_NUM; e++) red[w][e] = p[e];
    }
    __syncthreads();
    if (threadIdx.x == 0) {
        float l[E_NUM];
#pragma unroll
        for (int e = 0; e < E_NUM; e++)
            l[e] = red[0][e] + red[1][e] + red[2][e] + red[3][e] + rb[e];
        int e0 = 0;
#pragma unroll
        for (int e = 1; e < E_NUM; e++) if (l[e] > l[e0]) e0 = e;
        int e1 = (e0 == 0) ? 1 : 0;
#pragma unroll
        for (int e = 0; e < E_NUM; e++) if (e != e0 && l[e] > l[e1]) e1 = e;
        float g0 = 1.f / (1.f + expf(l[e1] - l[e0]));
        float g1 = 1.f - g0;
        int p0 = atomicAdd(&counts[e0], 1);
        tok[e0 * NTOK + p0] = (uint32_t)t;
        gate[e0 * NTOK + p0] = g0;
        int p1 = atomicAdd(&counts[e1], 1);
        tok[e1 * NTOK + p1] = (uint32_t)t | (1u << 16);
        gate[e1 * NTOK + p1] = g1;
    }
}

// ---------------- K2: fp32 -> bf16 convert (no transpose) --------------------
__global__ __launch_bounds__(256) void cvt_bf16_kernel(
    const float* __restrict__ src, unsigned short* __restrict__ dst, int n4) {
    int i = blockIdx.x * 256 + threadIdx.x;
    if (i >= n4) return;
    float4 v = ((const float4*)src)[i];
    ushort4 o;
    o.x = f2bf(v.x); o.y = f2bf(v.y); o.z = f2bf(v.z); o.w = f2bf(v.w);
    ((ushort4*)dst)[i] = o;
}

// ---------------- K3: fp32 [K][N] -> bf16 [N][K] transpose -------------------
__global__ __launch_bounds__(256) void transpose_cvt_kernel(
    const float* __restrict__ src, unsigned short* __restrict__ dst,
    int K_, int N_) {
    __shared__ unsigned short tile[64][72];
    size_t moff = (size_t)blockIdx.z * (size_t)K_ * N_;
    const float* s = src + moff;
    unsigned short* d = dst + moff;
    int k0 = blockIdx.y * 64, n0 = blockIdx.x * 64;
    int r = threadIdx.x >> 4;
    int c = (threadIdx.x & 15) * 4;
#pragma unroll
    for (int p = 0; p < 4; p++) {
        int k = p * 16 + r;
        float4 v = *(const float4*)(s + (size_t)(k0 + k) * N_ + n0 + c);
        tile[k][c + 0] = f2bf(v.x);
        tile[k][c + 1] = f2bf(v.y);
        tile[k][c + 2] = f2bf(v.z);
        tile[k][c + 3] = f2bf(v.w);
    }
    __syncthreads();
#pragma unroll
    for (int p = 0; p < 4; p++) {
        int n = p * 16 + r;
        ushort4 o;
        o.x = tile[c + 0][n];
        o.y = tile[c + 1][n];
        o.z = tile[c + 2][n];
        o.w = tile[c + 3][n];
        *(ushort4*)(d + (size_t)(n0 + n) * K_ + k0 + c) = o;
    }
}

// ---------------- K4: grouped gathered expert GEMM + gelu + gate -------------
__global__ __launch_bounds__(256) void expert_gemm_kernel(
    const unsigned short* __restrict__ xb,   // [NTOK][H] bf16
    const unsigned short* __restrict__ ewT,  // [E][D][H] bf16
    const float* __restrict__ eb,            // [E][D]
    const int* __restrict__ counts,
    const uint32_t* __restrict__ tok,
    const float* __restrict__ gate,
    unsigned short* __restrict__ Y)          // [NTOK][2][D] bf16
{
    int e = blockIdx.z;
    int cnt = counts[e];
    int m0 = blockIdx.y * BM;
    if (m0 >= cnt) return;
    int n0 = blockIdx.x * BN;

    __shared__ unsigned short As[BM][BK + 8];
    __shared__ unsigned short Bs[BN][BK + 8];
    __shared__ uint32_t tok_s[BM];
    __shared__ float gate_s[BM];

    int tid = threadIdx.x;
    if (tid < BM) {
        int idx = m0 + tid;
        uint32_t tk = 0; float g = 0.f;
        if (idx < cnt) { tk = tok[e * NTOK + idx]; g = gate[e * NTOK + idx]; }
        tok_s[tid] = tk; gate_s[tid] = g;
    }
    __syncthreads();

    int ar = tid >> 2;          // 0..63 staging row
    int ac = (tid & 3) * 8;     // element offset within 32-wide row chunk
    const unsigned short* ag0 = xb + (size_t)(tok_s[ar] & 0xFFFFu) * H_DIM + ac;
    const unsigned short* ag1 = xb + (size_t)(tok_s[ar + 64] & 0xFFFFu) * H_DIM + ac;
    const unsigned short* bbase = ewT + (size_t)e * D_DIM * H_DIM;
    const unsigned short* bg0 = bbase + (size_t)(n0 + ar) * H_DIM + ac;
    const unsigned short* bg1 = bg0 + (size_t)64 * H_DIM;

    int lane = tid & 63;
    int wave = tid >> 6;
    int wm = (wave >> 1) * 64;
    int wn = (wave & 1) * 64;
    int row16 = lane & 15;
    int quad = lane >> 4;
    int k8 = quad * 8;

    f32x4 acc[4][4];
#pragma unroll
    for (int i = 0; i < 4; i++)
#pragma unroll
        for (int j = 0; j < 4; j++) acc[i][j] = (f32x4)(0.f);

    for (int kk = 0; kk < H_DIM; kk += BK) {
        uint4 a0 = *(const uint4*)(ag0 + kk);
        uint4 a1 = *(const uint4*)(ag1 + kk);
        uint4 b0 = *(const uint4*)(bg0 + kk);
        uint4 b1 = *(const uint4*)(bg1 + kk);
        __syncthreads();
        *(uint4*)&As[ar][ac] = a0;
        *(uint4*)&As[ar + 64][ac] = a1;
        *(uint4*)&Bs[ar][ac] = b0;
        *(uint4*)&Bs[ar + 64][ac] = b1;
        __syncthreads();
        bf16x8 af[4], bff[4];
#pragma unroll
        for (int i = 0; i < 4; i++)
            af[i] = *(const bf16x8*)&As[wm + i * 16 + row16][k8];
#pragma unroll
        for (int j = 0; j < 4; j++)
            bff[j] = *(const bf16x8*)&Bs[wn + j * 16 + row16][k8];
#pragma unroll
        for (int i = 0; i < 4; i++)
#pragma unroll
            for (int j = 0; j < 4; j++)
                acc[i][j] = __builtin_amdgcn_mfma_f32_16x16x32_bf16(
                    af[i], bff[j], acc[i][j], 0, 0, 0);
    }

    // epilogue: bias + gelu(tanh approx == x*sigmoid(2z)) + gate, scatter to Y
#pragma unroll
    for (int i = 0; i < 4; i++) {
        int rbase = wm + i * 16 + quad * 4;
#pragma unroll
        for (int j = 0; j < 4; j++) {
            int n = n0 + wn + j * 16 + row16;
            float bias = eb[e * D_DIM + n];
#pragma unroll
            for (int r = 0; r < 4; r++) {
                int lrow = rbase + r;
                if (m0 + lrow < cnt) {
                    uint32_t tk = tok_s[lrow];
                    float g = gate_s[lrow];
                    float v = acc[i][j][r] + bias;
                    float q = 0.7978845608028654f * (v + 0.044715f * v * v * v);
                    float gl = v / (1.f + __expf(-2.f * q));
                    int token = tk & 0xFFFF;
                    int slot = (tk >> 16) & 1;
                    Y[((size_t)token * 2 + slot) * D_DIM + n] = f2bf(g * gl);
                }
            }
        }
    }
}

// ---------------- K5: combine slot0+slot1 -> bf16 combined -------------------
__global__ __launch_bounds__(256) void combine_kernel(
    const unsigned short* __restrict__ Y, unsigned short* __restrict__ comb) {
    int i = blockIdx.x * 256 + threadIdx.x;  // over NTOK*D/8
    int t = i >> 8;
    int dc = (i & 255) * 8;
    uint4 u0 = *(const uint4*)(Y + (size_t)t * 2 * D_DIM + dc);
    uint4 u1 = *(const uint4*)(Y + ((size_t)t * 2 + 1) * D_DIM + dc);
    uint4 o;
    uint32_t* po = (uint32_t*)&o;
    const uint32_t* p0 = (const uint32_t*)&u0;
    const uint32_t* p1 = (const uint32_t*)&u1;
#pragma unroll
    for (int k = 0; k < 4; k++) {
        uint32_t a = p0[k], b = p1[k];
        float s0 = bf2f((unsigned short)(a & 0xFFFF)) + bf2f((unsigned short)(b & 0xFFFF));
        float s1 = bf2f((unsigned short)(a >> 16)) + bf2f((unsigned short)(b >> 16));
        po[k] = (uint32_t)f2bf(s0) | ((uint32_t)f2bf(s1) << 16);
    }
    *(uint4*)(comb + (size_t)t * D_DIM + dc) = o;
}

// ---------------- K6: output projection GEMM + bias -> fp32 out --------------
__global__ __launch_bounds__(256) void out_gemm_kernel(
    const unsigned short* __restrict__ comb,  // [NTOK][D] bf16
    const unsigned short* __restrict__ owT,   // [D][D] bf16 (owT[n][k]=ow[k][n])
    const float* __restrict__ ob,
    float* __restrict__ out) {
    int m0 = blockIdx.y * BM, n0 = blockIdx.x * BN;
    __shared__ unsigned short As[BM][BK + 8];
    __shared__ unsigned short Bs[BN][BK + 8];
    int tid = threadIdx.x;
    int ar = tid >> 2;
    int ac = (tid & 3) * 8;
    const unsigned short* ag0 = comb + (size_t)(m0 + ar) * D_DIM + ac;
    const unsigned short* ag1 = ag0 + (size_t)64 * D_DIM;
    const unsigned short* bg0 = owT + (size_t)(n0 + ar) * D_DIM + ac;
    const unsigned short* bg1 = bg0 + (size_t)64 * D_DIM;

    int lane = tid & 63;
    int wave = tid >> 6;
    int wm = (wave >> 1) * 64;
    int wn = (wave & 1) * 64;
    int row16 = lane & 15;
    int quad = lane >> 4;
    int k8 = quad * 8;

    f32x4 acc[4][4];
#pragma unroll
    for (int i = 0; i < 4; i++)
#pragma unroll
        for (int j = 0; j < 4; j++) acc[i][j] = (f32x4)(0.f);

    for (int kk = 0; kk < D_DIM; kk += BK) {
        uint4 a0 = *(const uint4*)(ag0 + kk);
        uint4 a1 = *(const uint4*)(ag1 + kk);
        uint4 b0 = *(const uint4*)(bg0 + kk);
        uint4 b1 = *(const uint4*)(bg1 + kk);
        __syncthreads();
        *(uint4*)&As[ar][ac] = a0;
        *(uint4*)&As[ar + 64][ac] = a1;
        *(uint4*)&Bs[ar][ac] = b0;
        *(uint4*)&Bs[ar + 64][ac] = b1;
        __syncthreads();
        bf16x8 af[4], bff[4];
#pragma unroll
        for (int i = 0; i < 4; i++)
            af[i] = *(const bf16x8*)&As[wm + i * 16 + row16][k8];
#pragma unroll
        for (int j = 0; j < 4; j++)
            bff[j] = *(const bf16x8*)&Bs[wn + j * 16 + row16][k8];
#pragma unroll
        for (int i = 0; i < 4; i++)
#pragma unroll
            for (int j = 0; j < 4; j++)
                acc[i][j] = __builtin_amdgcn_mfma_f32_16x16x32_bf16(
                    af[i], bff[j], acc[i][j], 0, 0, 0);
    }

#pragma unroll
    for (int i = 0; i < 4; i++) {
        int rbase = m0 + wm + i * 16 + quad * 4;
#pragma unroll
        for (int j = 0; j < 4; j++) {
            int n = n0 + wn + j * 16 + row16;
            float bias = ob[n];
#pragma unroll
            for (int r = 0; r < 4; r++) {
                out[(size_t)(rbase + r) * D_DIM + n] = acc[i][j][r] + bias;
            }
        }
    }
}

extern "C" void kernel_launch(void* const* d_in, const int* in_sizes, int n_in,
                              void* d_out, int out_size, void* d_ws, size_t ws_size,
                              hipStream_t stream) {
    const float* x        = (const float*)d_in[0];  // [4096, 2048]
    const float* router_w = (const float*)d_in[1];  // [2048, 8]
    const float* router_b = (const float*)d_in[2];  // [8]
    const float* expert_w = (const float*)d_in[3];  // [8, 2048, 2048]
    const float* expert_b = (const float*)d_in[4];  // [8, 2048]
    const float* out_w    = (const float*)d_in[5];  // [2048, 2048]
    const float* out_b    = (const float*)d_in[6];  // [2048]
    float* out = (float*)d_out;                     // [4096, 2048]

    char* w = (char*)d_ws;
    int* counts = (int*)w;
    uint32_t* tok = (uint32_t*)(w + 256);
    float* gate = (float*)(w + 256 + E_NUM * NTOK * 4);
    size_t off = 256 + (size_t)2 * E_NUM * NTOK * 4;
    unsigned short* xb = (unsigned short*)(w + off);
    off += (size_t)NTOK * H_DIM * 2;
    unsigned short* ewT = (unsigned short*)(w + off);
    off += (size_t)E_NUM * H_DIM * D_DIM * 2;
    unsigned short* owT = (unsigned short*)(w + off);
    off += (size_t)D_DIM * D_DIM * 2;
    unsigned short* Y = (unsigned short*)(w + off);
    off += (size_t)NTOK * 2 * D_DIM * 2;
    unsigned short* comb = (unsigned short*)(w + off);

    hipMemsetAsync(d_ws, 0, 256, stream);
    router_kernel<<<NTOK, 256, 0, stream>>>(x, router_w, router_b, counts, tok, gate);
    cvt_bf16_kernel<<<(NTOK * H_DIM / 4 + 255) / 256, 256, 0, stream>>>(x, xb, NTOK * H_DIM / 4);
    transpose_cvt_kernel<<<dim3(32, 32, 8), 256, 0, stream>>>(expert_w, ewT, H_DIM, D_DIM);
    transpose_cvt_kernel<<<dim3(32, 32, 1), 256, 0, stream>>>(out_w, owT, D_DIM, D_DIM);
    expert_gemm_kernel<<<dim3(16, 32, 8), 256, 0, stream>>>(xb, ewT, expert_b, counts, tok, gate, Y);
    combine_kernel<<<NTOK * D_DIM / 8 / 256, 256, 0, stream>>>(Y, comb);
    out_gemm_kernel<<<dim3(16, 32), 256, 0, stream>>>(comb, owT, out_b, out);
}

// Round 2
// 534.695 us; speedup vs baseline: 1.0555x; 1.0555x over previous
//
#include <hip/hip_runtime.h>
#include <stdint.h>

#define H_DIM 2048
#define E_NUM 8
#define D_DIM 2048
#define NTOK 4096
#define BM 128
#define BN 128
#define BK 32

typedef __bf16 bf16x8 __attribute__((ext_vector_type(8)));
typedef float f32x4 __attribute__((ext_vector_type(4)));

__device__ __forceinline__ unsigned short f2bf(float f) {
    union { float f; uint32_t u; } c; c.f = f;
    uint32_t r = (c.u + 0x7FFFu + ((c.u >> 16) & 1u)) >> 16;
    return (unsigned short)r;
}
__device__ __forceinline__ float bf2f(unsigned short h) {
    union { float f; uint32_t u; } c; c.u = ((uint32_t)h) << 16;
    return c.f;
}

// async global->LDS, 16B per lane; LDS dest must be wave-uniform base.
__device__ __forceinline__ void gl_lds16(const unsigned short* g, unsigned short* l) {
    __builtin_amdgcn_global_load_lds(
        (const __attribute__((address_space(1))) unsigned int*)g,
        (__attribute__((address_space(3))) unsigned int*)l, 16, 0, 0);
}

// ------- K1: router, wave-per-token, fused x -> bf16 conversion -------------
__global__ __launch_bounds__(256) void router_cvt_kernel(
    const float* __restrict__ x, const float* __restrict__ rw,
    const float* __restrict__ rb, int* __restrict__ counts,
    uint32_t* __restrict__ tok, float* __restrict__ gate,
    unsigned short* __restrict__ xb) {
    int t = (blockIdx.x * 256 + threadIdx.x) >> 6;  // token = global wave id
    int lane = threadIdx.x & 63;
    const float* xr = x + (size_t)t * H_DIM;
    unsigned short* xo = xb + (size_t)t * H_DIM;
    float p[E_NUM];
#pragma unroll
    for (int e = 0; e < E_NUM; e++) p[e] = 0.f;
#pragma unroll
    for (int pass = 0; pass < H_DIM / 256; pass++) {
        int h = pass * 256 + lane * 4;
        float4 v = *(const float4*)(xr + h);
        ushort4 o;
        o.x = f2bf(v.x); o.y = f2bf(v.y); o.z = f2bf(v.z); o.w = f2bf(v.w);
        *(ushort4*)(xo + h) = o;
        const float* r0 = rw + (size_t)h * E_NUM;
#pragma unroll
        for (int e = 0; e < E_NUM; e++)
            p[e] += v.x * r0[e] + v.y * r0[e + 8] + v.z * r0[e + 16] + v.w * r0[e + 24];
    }
#pragma unroll
    for (int e = 0; e < E_NUM; e++) {
#pragma unroll
        for (int off = 1; off < 64; off <<= 1) p[e] += __shfl_xor(p[e], off, 64);
    }
    if (lane == 0) {
        float l[E_NUM];
#pragma unroll
        for (int e = 0; e < E_NUM; e++) l[e] = p[e] + rb[e];
        int e0 = 0;
#pragma unroll
        for (int e = 1; e < E_NUM; e++) if (l[e] > l[e0]) e0 = e;
        int e1 = (e0 == 0) ? 1 : 0;
#pragma unroll
        for (int e = 0; e < E_NUM; e++) if (e != e0 && l[e] > l[e1]) e1 = e;
        float g0 = 1.f / (1.f + __expf(l[e1] - l[e0]));
        float g1 = 1.f - g0;
        int p0 = atomicAdd(&counts[e0], 1);
        tok[e0 * NTOK + p0] = (uint32_t)t;
        gate[e0 * NTOK + p0] = g0;
        int p1 = atomicAdd(&counts[e1], 1);
        tok[e1 * NTOK + p1] = (uint32_t)t | (1u << 16);
        gate[e1 * NTOK + p1] = g1;
    }
}

// ------- K2: fp32 [K][N] -> bf16 [N][K] transpose ---------------------------
__global__ __launch_bounds__(256) void transpose_cvt_kernel(
    const float* __restrict__ src, unsigned short* __restrict__ dst,
    int K_, int N_) {
    __shared__ unsigned short tile[64][72];
    size_t moff = (size_t)blockIdx.z * (size_t)K_ * N_;
    const float* s = src + moff;
    unsigned short* d = dst + moff;
    int k0 = blockIdx.y * 64, n0 = blockIdx.x * 64;
    int r = threadIdx.x >> 4;
    int c = (threadIdx.x & 15) * 4;
#pragma unroll
    for (int p = 0; p < 4; p++) {
        int k = p * 16 + r;
        float4 v = *(const float4*)(s + (size_t)(k0 + k) * N_ + n0 + c);
        tile[k][c + 0] = f2bf(v.x);
        tile[k][c + 1] = f2bf(v.y);
        tile[k][c + 2] = f2bf(v.z);
        tile[k][c + 3] = f2bf(v.w);
    }
    __syncthreads();
#pragma unroll
    for (int p = 0; p < 4; p++) {
        int n = p * 16 + r;
        ushort4 o;
        o.x = tile[c + 0][n];
        o.y = tile[c + 1][n];
        o.z = tile[c + 2][n];
        o.w = tile[c + 3][n];
        *(ushort4*)(d + (size_t)(n0 + n) * K_ + k0 + c) = o;
    }
}

// ------- K3: grouped gathered expert GEMM + gelu + gate ---------------------
__global__ __launch_bounds__(256) void expert_gemm_kernel(
    const unsigned short* __restrict__ xb,   // [NTOK][H] bf16
    const unsigned short* __restrict__ ewT,  // [E][D][H] bf16
    const float* __restrict__ eb,            // [E][D]
    const int* __restrict__ counts,
    const uint32_t* __restrict__ tok,
    const float* __restrict__ gate,
    unsigned short* __restrict__ Y)          // [NTOK][2][D] bf16
{
    int e = blockIdx.z;
    int cnt = counts[e];
    int m0 = blockIdx.y * BM;
    if (m0 >= cnt) return;
    int n0 = blockIdx.x * BN;

    __shared__ unsigned short As[BM][BK];    // unpadded: global_load_lds layout
    __shared__ unsigned short Bs[BN][BK];
    __shared__ uint32_t tok_s[BM];
    __shared__ float gate_s[BM];

    int tid = threadIdx.x;
    if (tid < BM) {
        int idx = m0 + tid;
        uint32_t tk = 0; float g = 0.f;
        if (idx < cnt) { tk = tok[e * NTOK + idx]; g = gate[e * NTOK + idx]; }
        tok_s[tid] = tk; gate_s[tid] = g;
    }
    __syncthreads();

    int lane = tid & 63;
    int wave = tid >> 6;
    // staging: each wave issues 2 A-loads + 2 B-loads of 16 rows x 32 cols.
    int sr = lane >> 2;                 // 0..15 row within 16-row group
    int sc = (lane & 3) * 8;            // 0,8,16,24 col chunk
    int r0 = wave * 32 + sr;
    int r1 = wave * 32 + 16 + sr;
    const unsigned short* agp0 = xb + (size_t)(tok_s[r0] & 0xFFFFu) * H_DIM + sc;
    const unsigned short* agp1 = xb + (size_t)(tok_s[r1] & 0xFFFFu) * H_DIM + sc;
    const unsigned short* bbase = ewT + (size_t)e * D_DIM * H_DIM;
    const unsigned short* bgp0 = bbase + (size_t)(n0 + r0) * H_DIM + sc;
    const unsigned short* bgp1 = bbase + (size_t)(n0 + r1) * H_DIM + sc;
    unsigned short* la0 = &As[wave * 32][0];
    unsigned short* la1 = &As[wave * 32 + 16][0];
    unsigned short* lb0 = &Bs[wave * 32][0];
    unsigned short* lb1 = &Bs[wave * 32 + 16][0];

    int wm = (wave >> 1) * 64;
    int wn = (wave & 1) * 64;
    int row16 = lane & 15;
    int quad = lane >> 4;
    int k8 = quad * 8;

    f32x4 acc[4][4];
#pragma unroll
    for (int i = 0; i < 4; i++)
#pragma unroll
        for (int j = 0; j < 4; j++) acc[i][j] = (f32x4)(0.f);

    for (int kk = 0; kk < H_DIM; kk += BK) {
        __syncthreads();                 // prior ds_reads done before overwrite
        gl_lds16(agp0 + kk, la0);
        gl_lds16(agp1 + kk, la1);
        gl_lds16(bgp0 + kk, lb0);
        gl_lds16(bgp1 + kk, lb1);
        __syncthreads();                 // vmcnt(0) drain -> tiles visible
        bf16x8 af[4], bff[4];
#pragma unroll
        for (int i = 0; i < 4; i++)
            af[i] = *(const bf16x8*)&As[wm + i * 16 + row16][k8];
#pragma unroll
        for (int j = 0; j < 4; j++)
            bff[j] = *(const bf16x8*)&Bs[wn + j * 16 + row16][k8];
#pragma unroll
        for (int i = 0; i < 4; i++)
#pragma unroll
            for (int j = 0; j < 4; j++)
                acc[i][j] = __builtin_amdgcn_mfma_f32_16x16x32_bf16(
                    af[i], bff[j], acc[i][j], 0, 0, 0);
    }

    // epilogue: bias + gelu(tanh form == v*sigmoid(2q)) * gate, scatter to Y
#pragma unroll
    for (int i = 0; i < 4; i++) {
        int rbase = wm + i * 16 + quad * 4;
#pragma unroll
        for (int j = 0; j < 4; j++) {
            int n = n0 + wn + j * 16 + row16;
            float bias = eb[e * D_DIM + n];
#pragma unroll
            for (int r = 0; r < 4; r++) {
                int lrow = rbase + r;
                if (m0 + lrow < cnt) {
                    uint32_t tk = tok_s[lrow];
                    float g = gate_s[lrow];
                    float v = acc[i][j][r] + bias;
                    float q = 0.7978845608028654f * (v + 0.044715f * v * v * v);
                    float gl = v / (1.f + __expf(-2.f * q));
                    int token = tk & 0xFFFF;
                    int slot = (tk >> 16) & 1;
                    Y[((size_t)token * 2 + slot) * D_DIM + n] = f2bf(g * gl);
                }
            }
        }
    }
}

// ------- K4: combine slot0+slot1 -> bf16 combined ---------------------------
__global__ __launch_bounds__(256) void combine_kernel(
    const unsigned short* __restrict__ Y, unsigned short* __restrict__ comb) {
    int i = blockIdx.x * 256 + threadIdx.x;  // over NTOK*D/8
    int t = i >> 8;
    int dc = (i & 255) * 8;
    uint4 u0 = *(const uint4*)(Y + (size_t)t * 2 * D_DIM + dc);
    uint4 u1 = *(const uint4*)(Y + ((size_t)t * 2 + 1) * D_DIM + dc);
    uint4 o;
    uint32_t* po = (uint32_t*)&o;
    const uint32_t* p0 = (const uint32_t*)&u0;
    const uint32_t* p1 = (const uint32_t*)&u1;
#pragma unroll
    for (int k = 0; k < 4; k++) {
        uint32_t a = p0[k], b = p1[k];
        float s0 = bf2f((unsigned short)(a & 0xFFFF)) + bf2f((unsigned short)(b & 0xFFFF));
        float s1 = bf2f((unsigned short)(a >> 16)) + bf2f((unsigned short)(b >> 16));
        po[k] = (uint32_t)f2bf(s0) | ((uint32_t)f2bf(s1) << 16);
    }
    *(uint4*)(comb + (size_t)t * D_DIM + dc) = o;
}

// ------- K5: output projection GEMM + bias -> fp32 out ----------------------
__global__ __launch_bounds__(256) void out_gemm_kernel(
    const unsigned short* __restrict__ comb,  // [NTOK][D] bf16
    const unsigned short* __restrict__ owT,   // [D][D] bf16
    const float* __restrict__ ob,
    float* __restrict__ out) {
    int m0 = blockIdx.y * BM, n0 = blockIdx.x * BN;
    __shared__ unsigned short As[BM][BK];
    __shared__ unsigned short Bs[BN][BK];
    int tid = threadIdx.x;
    int lane = tid & 63;
    int wave = tid >> 6;
    int sr = lane >> 2;
    int sc = (lane & 3) * 8;
    int r0 = wave * 32 + sr;
    int r1 = wave * 32 + 16 + sr;
    const unsigned short* agp0 = comb + (size_t)(m0 + r0) * D_DIM + sc;
    const unsigned short* agp1 = comb + (size_t)(m0 + r1) * D_DIM + sc;
    const unsigned short* bgp0 = owT + (size_t)(n0 + r0) * D_DIM + sc;
    const unsigned short* bgp1 = owT + (size_t)(n0 + r1) * D_DIM + sc;
    unsigned short* la0 = &As[wave * 32][0];
    unsigned short* la1 = &As[wave * 32 + 16][0];
    unsigned short* lb0 = &Bs[wave * 32][0];
    unsigned short* lb1 = &Bs[wave * 32 + 16][0];

    int wm = (wave >> 1) * 64;
    int wn = (wave & 1) * 64;
    int row16 = lane & 15;
    int quad = lane >> 4;
    int k8 = quad * 8;

    f32x4 acc[4][4];
#pragma unroll
    for (int i = 0; i < 4; i++)
#pragma unroll
        for (int j = 0; j < 4; j++) acc[i][j] = (f32x4)(0.f);

    for (int kk = 0; kk < D_DIM; kk += BK) {
        __syncthreads();
        gl_lds16(agp0 + kk, la0);
        gl_lds16(agp1 + kk, la1);
        gl_lds16(bgp0 + kk, lb0);
        gl_lds16(bgp1 + kk, lb1);
        __syncthreads();
        bf16x8 af[4], bff[4];
#pragma unroll
        for (int i = 0; i < 4; i++)
            af[i] = *(const bf16x8*)&As[wm + i * 16 + row16][k8];
#pragma unroll
        for (int j = 0; j < 4; j++)
            bff[j] = *(const bf16x8*)&Bs[wn + j * 16 + row16][k8];
#pragma unroll
        for (int i = 0; i < 4; i++)
#pragma unroll
            for (int j = 0; j < 4; j++)
                acc[i][j] = __builtin_amdgcn_mfma_f32_16x16x32_bf16(
                    af[i], bff[j], acc[i][j], 0, 0, 0);
    }

#pragma unroll
    for (int i = 0; i < 4; i++) {
        int rbase = m0 + wm + i * 16 + quad * 4;
#pragma unroll
        for (int j = 0; j < 4; j++) {
            int n = n0 + wn + j * 16 + row16;
            float bias = ob[n];
#pragma unroll
            for (int r = 0; r < 4; r++) {
                out[(size_t)(rbase + r) * D_DIM + n] = acc[i][j][r] + bias;
            }
        }
    }
}

extern "C" void kernel_launch(void* const* d_in, const int* in_sizes, int n_in,
                              void* d_out, int out_size, void* d_ws, size_t ws_size,
                              hipStream_t stream) {
    const float* x        = (const float*)d_in[0];  // [4096, 2048]
    const float* router_w = (const float*)d_in[1];  // [2048, 8]
    const float* router_b = (const float*)d_in[2];  // [8]
    const float* expert_w = (const float*)d_in[3];  // [8, 2048, 2048]
    const float* expert_b = (const float*)d_in[4];  // [8, 2048]
    const float* out_w    = (const float*)d_in[5];  // [2048, 2048]
    const float* out_b    = (const float*)d_in[6];  // [2048]
    float* out = (float*)d_out;                     // [4096, 2048]

    char* w = (char*)d_ws;
    int* counts = (int*)w;
    uint32_t* tok = (uint32_t*)(w + 256);
    float* gate = (float*)(w + 256 + E_NUM * NTOK * 4);
    size_t off = 256 + (size_t)2 * E_NUM * NTOK * 4;
    unsigned short* xb = (unsigned short*)(w + off);
    off += (size_t)NTOK * H_DIM * 2;
    unsigned short* ewT = (unsigned short*)(w + off);
    off += (size_t)E_NUM * H_DIM * D_DIM * 2;
    unsigned short* owT = (unsigned short*)(w + off);
    off += (size_t)D_DIM * D_DIM * 2;
    unsigned short* Y = (unsigned short*)(w + off);
    off += (size_t)NTOK * 2 * D_DIM * 2;
    unsigned short* comb = (unsigned short*)(w + off);

    hipMemsetAsync(d_ws, 0, 256, stream);
    router_cvt_kernel<<<NTOK / 4, 256, 0, stream>>>(x, router_w, router_b,
                                                    counts, tok, gate, xb);
    transpose_cvt_kernel<<<dim3(32, 32, 8), 256, 0, stream>>>(expert_w, ewT, H_DIM, D_DIM);
    transpose_cvt_kernel<<<dim3(32, 32, 1), 256, 0, stream>>>(out_w, owT, D_DIM, D_DIM);
    expert_gemm_kernel<<<dim3(16, 32, 8), 256, 0, stream>>>(xb, ewT, expert_b, counts, tok, gate, Y);
    combine_kernel<<<NTOK * D_DIM / 8 / 256, 256, 0, stream>>>(Y, comb);
    out_gemm_kernel<<<dim3(16, 32), 256, 0, stream>>>(comb, owT, out_b, out);
}